// Round 9
// baseline (156.043 us; speedup 1.0000x reference)
//
#include <hip/hip_runtime.h>

// MTH spiking-threshold recurrence: elementwise over N = B*C*H*W, T=4, K=8.
// x: [T+1, N] (plane 0 = bias). out: [T+1, N] (plane 0 = zeros).
//
// Structure (R4): 1 float4-chunk per thread; 5 loads upfront into distinct
// registers; ALL 5 stores at the end from distinct never-redefined registers
// (no vmcnt wait on store retirement -> wave slot frees at s_endpgm while
// stores drain). Target <=64 VGPR for 8 waves/SIMD.
//
// Exactness (absmax must be 0):
//  - th == 1.0f path: thre[k]=2^-k, tt[k]=0.75*2^-k exact; same-sign IEEE
//    compares == integer compares on bit patterns -> integer threshold pick.
//  - spike/3 = (+-2^-k)/3 = 2^-k * RN(1/3) exactly -> one multiply.
//  - d/3 via Markstein: q=RN(d*RN(1/3)); r=fma(-3,q,d) exact; fma(r,c,q)
//    is the correctly-rounded binary32 quotient -> bit-identical to IEEE div.
//  - mem update keeps reference association: (((mem+xt)-bias)+ein)-eout.

constexpr int T_STEPS = 4;
constexpr int K_THR   = 8;

typedef float f32x4 __attribute__((ext_vector_type(4)));

__device__ __forceinline__ float div3_cr(float v) {
    const float c = 1.0f / 3.0f;
    float q = v * c;
    float r = __builtin_fmaf(-3.0f, q, v);
    return __builtin_fmaf(r, c, q);
}

// spike for th == 1.0 exactly: integer threshold selection, bit-exact.
__device__ __forceinline__ float spike_fast(float m, float c) {
    const unsigned B075 = 0x3F400000u;   // bits(0.75f) = bits(tt[0])
    const unsigned B100 = 0x3F800000u;   // bits(1.0f)  = bits(thre[0])
    const float TT7 = 0.0058593750f;     // 0.75 * 2^-7
    const float TH7 = 0.0078125f;        // 2^-7

    const unsigned mb = (unsigned)__float_as_int(m);

    // positive: smallest k with m >= 0.75*2^-k (valid iff m >= tt[7] > 0)
    int dp = (int)(B075 - mb);
    int kp = (dp + 0x7FFFFF) >> 23;      // ceil(dp / 2^23)
    kp = kp < 0 ? 0 : kp;
    const float spv = __int_as_float((127 - kp) << 23);   // 2^-kp
    const float sp  = (m >= TT7) ? spv : 0.0f;

    // negative: smallest k with (|m| >= tt[k]) && (c >= 2^-k)
    int da = (int)(B075 - (mb & 0x7FFFFFFFu));
    int ka = (da + 0x7FFFFF) >> 23;
    ka = ka < 0 ? 0 : ka;
    int db = (int)(B100 - (unsigned)__float_as_int(c));
    int kb = (db + 0x7FFFFF) >> 23;
    kb = kb < 0 ? 0 : kb;
    const int kn = ka > kb ? ka : kb;
    const float snv = __int_as_float((127 - kn) << 23);   // 2^-kn
    const float sn  = (m <= -TT7 && c >= TH7) ? snv : 0.0f;

    return sp - sn;   // at most one nonzero -> exact
}

// general-th fallback (never taken in this bench; kept for correctness)
__device__ __forceinline__ float spike_general(float m, float c, float th) {
    float sp = 0.f, sn = 0.f;
    #pragma unroll
    for (int k = K_THR - 1; k >= 0; --k) {
        const float thre = th * (1.0f / (float)(1 << k));
        const float tt   = 0.75f * thre;
        sp = (m >= tt) ? thre : sp;
        sn = (m <= -tt && c >= thre) ? thre : sn;
    }
    return sp - sn;
}

template <bool FAST>
__device__ __forceinline__ void run_body(const f32x4* __restrict__ xv,
                                         f32x4* __restrict__ ov,
                                         float th, int n4, int i)
{
    // ---- phase 1: issue ALL 5 loads into distinct registers -------------
    const f32x4 b4 = xv[i];
    const f32x4 x1 = xv[(size_t)1 * n4 + i];
    const f32x4 x2 = xv[(size_t)2 * n4 + i];
    const f32x4 x3 = xv[(size_t)3 * n4 + i];
    const f32x4 x4 = xv[(size_t)4 * n4 + i];

    // ---- phase 2: compute all 4 spike planes into distinct registers ----
    f32x4 s1, s2, s3, s4;

    #pragma unroll
    for (int j = 0; j < 4; ++j) {
        const float b  = b4[j];
        float mem = 0.f, cum = 0.f, ein = b, eout = 0.f;

        // t = 0 (denom 1)
        {
            const float xt = x1[j];
            float m = (((mem + xt) - b) + ein) - eout;
            float c = cum + eout;
            const float spike = FAST ? spike_fast(m, c) : spike_general(m, c, th);
            m -= spike; c += spike;
            ein  += (xt - b);
            eout += spike;
            mem = m; cum = c; s1[j] = spike;
        }
        // t = 1 (denom 2 -> exact *0.5)
        {
            const float xt = x2[j];
            float m = (((mem + xt) - b) + ein) - eout;
            float c = cum + eout;
            const float spike = FAST ? spike_fast(m, c) : spike_general(m, c, th);
            m -= spike; c += spike;
            ein  += (xt - b) * 0.5f;
            eout += spike * 0.5f;
            mem = m; cum = c; s2[j] = spike;
        }
        // t = 2 (denom 3 -> correctly-rounded via FMA; spike/3 exact mul)
        {
            const float xt = x3[j];
            float m = (((mem + xt) - b) + ein) - eout;
            float c = cum + eout;
            const float spike = FAST ? spike_fast(m, c) : spike_general(m, c, th);
            m -= spike; c += spike;
            ein  += div3_cr(xt - b);
            eout += FAST ? (spike * (1.0f / 3.0f)) : div3_cr(spike);
            mem = m; cum = c; s3[j] = spike;
        }
        // t = 3 (denom 4 -> exact *0.25); state after this is dead
        {
            const float xt = x4[j];
            float m = (((mem + xt) - b) + ein) - eout;
            float c = cum + eout;
            const float spike = FAST ? spike_fast(m, c) : spike_general(m, c, th);
            s4[j] = spike;
        }
    }

    // ---- phase 3: one burst of stores, all from distinct live regs ------
    __builtin_nontemporal_store((f32x4){0.f, 0.f, 0.f, 0.f}, &ov[i]);
    __builtin_nontemporal_store(s1, &ov[(size_t)1 * n4 + i]);
    __builtin_nontemporal_store(s2, &ov[(size_t)2 * n4 + i]);
    __builtin_nontemporal_store(s3, &ov[(size_t)3 * n4 + i]);
    __builtin_nontemporal_store(s4, &ov[(size_t)4 * n4 + i]);
}

__global__ __launch_bounds__(256) void mth_kernel(
    const float* __restrict__ x, const float* __restrict__ thresh,
    float* __restrict__ out, int n4)
{
    const float th = __uint_as_float(
        __builtin_amdgcn_readfirstlane(__float_as_uint(thresh[0])));

    const int i = blockIdx.x * 256 + threadIdx.x;
    if (i >= n4) return;

    const f32x4* __restrict__ xv = reinterpret_cast<const f32x4*>(x);
    f32x4* __restrict__ ov       = reinterpret_cast<f32x4*>(out);

    if (th == 1.0f) run_body<true >(xv, ov, th, n4, i);
    else            run_body<false>(xv, ov, th, n4, i);
}

extern "C" void kernel_launch(void* const* d_in, const int* in_sizes, int n_in,
                              void* d_out, int out_size, void* d_ws, size_t ws_size,
                              hipStream_t stream)
{
    const float* x      = (const float*)d_in[0];
    const float* thresh = (const float*)d_in[1];
    float* out          = (float*)d_out;

    const int N  = in_sizes[0] / (T_STEPS + 1);  // 4,194,304
    const int n4 = N / 4;                         // 1,048,576
    const int block = 256;
    const int grid  = (n4 + block - 1) / block;   // 4096 blocks

    mth_kernel<<<grid, block, 0, stream>>>(x, thresh, out, n4);
}